// Round 1
// baseline (180.534 us; speedup 1.0000x reference)
//
#include <hip/hip_runtime.h>

// MMD loss, class-compacted. Shapes (from reference): source (S_total=4096, D=512),
// target (T=2048, D), s_label (S_total,), t_label (T, C=31), nsd=2048 (device scalar).
// total = concat(source[nsd:], target)  -> N = (S_total-nsd) + T rows.

#define PAD 68  // LDS row stride in floats (16B aligned, conflict-free for our access)

__global__ void k_argmax(const float* __restrict__ tlabel, int* __restrict__ tlab,
                         int T, int C) {
  int t = blockIdx.x * blockDim.x + threadIdx.x;
  if (t >= T) return;
  const float* row = tlabel + (size_t)t * C;
  float best = row[0]; int bi = 0;
  for (int i = 1; i < C; i++) { float v = row[i]; if (v > best) { best = v; bi = i; } }
  tlab[t] = bi;
}

__global__ void k_sq(const float* __restrict__ src, const float* __restrict__ tgt,
                     const int* __restrict__ nsd_p, float* __restrict__ sq,
                     int S_total, int T, int D) {
  int nsd = nsd_p[0];
  int S_use = S_total - nsd;
  int N = S_use + T;
  int r = blockIdx.x;
  if (r >= N) return;
  const float* row = (r < S_use) ? (src + (size_t)(nsd + r) * D)
                                 : (tgt + (size_t)(r - S_use) * D);
  const float4* row4 = (const float4*)row;
  int n4 = D >> 2;
  float s = 0.f;
  for (int i = threadIdx.x; i < n4; i += 64) {
    float4 v = row4[i];
    s += v.x * v.x + v.y * v.y + v.z * v.z + v.w * v.w;
  }
  for (int o = 32; o > 0; o >>= 1) s += __shfl_down(s, o, 64);
  if (threadIdx.x == 0) sq[r] = s;
}

__global__ void k_count(const int* __restrict__ slab, const int* __restrict__ tlab,
                        const int* __restrict__ nsd_p,
                        int* cnt, int* srccnt, int* tgtcnt, int S_total, int T) {
  int nsd = nsd_p[0];
  int S_use = S_total - nsd;
  int N = S_use + T;
  int r = blockIdx.x * blockDim.x + threadIdx.x;
  if (r >= N) return;
  int c;
  if (r < S_use) { c = slab[nsd + r]; atomicAdd(&srccnt[c], 1); }
  else           { c = tlab[r - S_use]; atomicAdd(&tgtcnt[c], 1); }
  atomicAdd(&cnt[c], 1);
}

__global__ void k_scan(const int* __restrict__ cnt, int* offset, int* alloc,
                       int* tprefix, int* misc, int C) {
  if (threadIdx.x != 0 || blockIdx.x != 0) return;
  int o = 0, tt = 0;
  for (int c = 0; c < C; c++) {
    offset[c] = o; alloc[c] = o; tprefix[c] = tt;
    int n = cnt[c];
    int tpr = (n + 31) / 32;
    o += n; tt += tpr * tpr;
  }
  tprefix[C] = tt;
  misc[0] = tt;  // total tiles
  misc[1] = o;   // N
}

__global__ void k_assign(const int* __restrict__ slab, const int* __restrict__ tlab,
                         const int* __restrict__ nsd_p, const float* __restrict__ sq,
                         int* alloc, int* perm, float* sqc, float* sgnc,
                         int S_total, int T) {
  int nsd = nsd_p[0];
  int S_use = S_total - nsd;
  int N = S_use + T;
  int r = blockIdx.x * blockDim.x + threadIdx.x;
  if (r >= N) return;
  int c = (r < S_use) ? slab[nsd + r] : tlab[r - S_use];
  int pos = atomicAdd(&alloc[c], 1);
  perm[pos] = r;
  sqc[pos] = sq[r];
  sgnc[pos] = (r < S_use) ? 1.f : -1.f;
}

__global__ void k_gather(const float* __restrict__ src, const float* __restrict__ tgt,
                         const int* __restrict__ nsd_p, const int* __restrict__ perm,
                         float* __restrict__ compact, int S_total, int T, int D) {
  int nsd = nsd_p[0];
  int S_use = S_total - nsd;
  int N = S_use + T;
  int b = blockIdx.x;
  if (b >= N) return;
  int r = perm[b];
  const float* row = (r < S_use) ? (src + (size_t)(nsd + r) * D)
                                 : (tgt + (size_t)(r - S_use) * D);
  const float4* s4 = (const float4*)row;
  float4* d4 = (float4*)(compact + (size_t)b * D);
  int n4 = D >> 2;
  for (int i = threadIdx.x; i < n4; i += 64) d4[i] = s4[i];
}

// per-class column sums -> ||sum_x||^2  (for the algebraic m@D@m identity)
__global__ void k_colsum(const float* __restrict__ compact, const int* __restrict__ cnt,
                         const int* __restrict__ offset, float* normsum, int D) {
  int c = blockIdx.x;
  int col = blockIdx.y * 64 + threadIdx.x;
  int n = cnt[c], off = offset[c];
  float s = 0.f;
  const float* base = compact + (size_t)off * D + col;
  for (int i = 0; i < n; i++) s += base[(size_t)i * D];
  float acc = s * s;
  for (int o = 32; o > 0; o >>= 1) acc += __shfl_down(acc, o, 64);
  if (threadIdx.x == 0) atomicAdd(&normsum[c], acc);
}

__global__ void k_sqsum(const float* __restrict__ sqc, const int* __restrict__ cnt,
                        const int* __restrict__ offset, float* sqsum) {
  int c = blockIdx.x;
  int n = cnt[c], off = offset[c];
  float s = 0.f;
  for (int i = threadIdx.x; i < n; i += 64) s += sqc[off + i];
  for (int o = 32; o > 0; o >>= 1) s += __shfl_down(s, o, 64);
  if (threadIdx.x == 0) sqsum[c] = s;
}

__global__ void k_bw(const int* __restrict__ cnt, const float* __restrict__ sqsum,
                     const float* __restrict__ normsum, float* bwArr, int C) {
  int c = threadIdx.x;
  if (c >= C) return;
  float n = (float)cnt[c];
  float S1 = 2.f * n * sqsum[c] - 2.f * normsum[c];  // == m @ Dmat @ m (clamp negligible)
  float bw = S1 / fmaxf(n * n - n, 1.f);
  bw = (bw > 0.f) ? bw : 1.f;
  bw *= 0.25f;  // / KERNEL_MUL^(KERNEL_NUM//2) = / 4
  bwArr[c] = bw;
}

__global__ __launch_bounds__(256) void k_pairs(
    const float* __restrict__ compact, const float* __restrict__ sqc,
    const float* __restrict__ sgnc, const int* __restrict__ cnt,
    const int* __restrict__ offset, const int* __restrict__ tprefix,
    const int* __restrict__ misc, const float* __restrict__ bwArr,
    float* losssum, int D, int C) {
  __shared__ float As[32 * PAD];
  __shared__ float Bs[32 * PAD];
  __shared__ float red[4];
  int tileTotal = misc[0];
  int tid = threadIdx.x;
  int ty = tid >> 4, tx = tid & 15;
  for (int t = blockIdx.x; t < tileTotal; t += gridDim.x) {
    int c = 0;
    while (!(t >= tprefix[c] && t < tprefix[c + 1])) c++;
    int n = cnt[c], off = offset[c];
    int tpr = (n + 31) / 32;
    int lt = t - tprefix[c];
    int jt = lt / tpr, kt = lt % tpr;
    int jbase = jt * 32, kbase = kt * 32;

    float acc00 = 0.f, acc01 = 0.f, acc10 = 0.f, acc11 = 0.f;
    for (int d0 = 0; d0 < D; d0 += 64) {
      // stage 32 rows x 64 floats for A and B tiles (zero-pad rows >= n)
      #pragma unroll
      for (int it = 0; it < 2; it++) {
        int e = tid + 256 * it;
        int row = e >> 4;     // 0..31
        int c4 = e & 15;      // which float4 in the 64-float chunk
        int jr = jbase + row, kr = kbase + row;
        float4 av = make_float4(0.f, 0.f, 0.f, 0.f);
        float4 bv = av;
        if (jr < n) av = *(const float4*)(compact + (size_t)(off + jr) * D + d0 + c4 * 4);
        if (kr < n) bv = *(const float4*)(compact + (size_t)(off + kr) * D + d0 + c4 * 4);
        *(float4*)(As + row * PAD + c4 * 4) = av;
        *(float4*)(Bs + row * PAD + c4 * 4) = bv;
      }
      __syncthreads();
      #pragma unroll
      for (int dq = 0; dq < 16; dq++) {
        float4 a0 = *(const float4*)(As + ty * PAD + dq * 4);
        float4 a1 = *(const float4*)(As + (ty + 16) * PAD + dq * 4);
        float4 b0 = *(const float4*)(Bs + tx * PAD + dq * 4);
        float4 b1 = *(const float4*)(Bs + (tx + 16) * PAD + dq * 4);
        acc00 += a0.x * b0.x + a0.y * b0.y + a0.z * b0.z + a0.w * b0.w;
        acc01 += a0.x * b1.x + a0.y * b1.y + a0.z * b1.z + a0.w * b1.w;
        acc10 += a1.x * b0.x + a1.y * b0.y + a1.z * b0.z + a1.w * b0.w;
        acc11 += a1.x * b1.x + a1.y * b1.y + a1.z * b1.z + a1.w * b1.w;
      }
      __syncthreads();
    }

    float inv0 = 1.0f / bwArr[c];
    int j0 = jbase + ty, j1 = jbase + ty + 16;
    int k0 = kbase + tx, k1 = kbase + tx + 16;
    auto pv = [&](int j, int k, float dot) -> float {
      if (j >= n || k >= n) return 0.f;
      float d = sqc[off + j] + sqc[off + k] - 2.f * dot;
      d = fmaxf(d, 0.f);
      float s = inv0, kv = 0.f;
      #pragma unroll
      for (int i = 0; i < 5; i++) { kv += __expf(-d * s); s *= 0.5f; }
      return sgnc[off + j] * sgnc[off + k] * kv;
    };
    float contrib = pv(j0, k0, acc00) + pv(j0, k1, acc01) +
                    pv(j1, k0, acc10) + pv(j1, k1, acc11);
    for (int o = 32; o > 0; o >>= 1) contrib += __shfl_down(contrib, o, 64);
    if ((tid & 63) == 0) red[tid >> 6] = contrib;
    __syncthreads();
    if (tid == 0) atomicAdd(&losssum[c], red[0] + red[1] + red[2] + red[3]);
    // next iteration's first __syncthreads (after staging) protects As/Bs/red reuse
  }
}

__global__ void k_final(const int* __restrict__ cnt, const int* __restrict__ srccnt,
                        const int* __restrict__ tgtcnt, const float* __restrict__ losssum,
                        float* out, int C) {
  if (threadIdx.x != 0 || blockIdx.x != 0) return;
  float loss = 0.f, cv = 0.f;
  for (int c = 0; c < C; c++) {
    if (srccnt[c] > 0 && tgtcnt[c] > 0) {
      float n = (float)cnt[c];
      loss += losssum[c] / fmaxf(n * n, 1.f);
      cv += 1.f;
    }
  }
  out[0] = loss / fmaxf(cv, 1.f);
}

extern "C" void kernel_launch(void* const* d_in, const int* in_sizes, int n_in,
                              void* d_out, int out_size, void* d_ws, size_t ws_size,
                              hipStream_t stream) {
  const float* source = (const float*)d_in[0];
  const float* target = (const float*)d_in[1];
  const int* slab     = (const int*)d_in[2];
  const float* tlabel = (const float*)d_in[3];
  const int* nsd_p    = (const int*)d_in[4];
  float* out = (float*)d_out;

  int S_total = in_sizes[2];
  int D = in_sizes[0] / S_total;   // 512
  int T = in_sizes[1] / D;         // 2048
  int C = in_sizes[3] / T;         // 31
  int NMAX = S_total + T;          // 6144 (actual N read on device)

  // workspace layout (4-byte words)
  float* ws = (float*)d_ws;
  int* cnt     = (int*)ws;              // C   -- zeroed
  int* srccnt  = cnt + C;               // C   -- zeroed
  int* tgtcnt  = srccnt + C;            // C   -- zeroed
  int* alloc   = tgtcnt + C;            // C   -- zeroed (then set by k_scan)
  float* normsum = (float*)(alloc + C); // C   -- zeroed
  float* sqsum   = normsum + C;         // C   -- zeroed
  float* losssum = sqsum + C;           // C   -- zeroed
  int* offset  = (int*)(losssum + C);   // C
  int* tprefix = offset + C;            // C+1
  int* misc    = tprefix + C + 1;       // 2
  float* bwArr = (float*)(misc + 2);    // C

  float* sq   = ws + 1024;
  float* sqc  = sq + NMAX;
  float* sgnc = sqc + NMAX;
  int* perm   = (int*)(sgnc + NMAX);
  int* tlab   = perm + NMAX;
  int words_used = 1024 + 4 * NMAX + T;
  int cw = (words_used + 63) & ~63;     // 256B-align compact
  float* compact = ws + cw;             // NMAX * D floats

  hipMemsetAsync(d_ws, 0, (size_t)(7 * C) * sizeof(int), stream);

  k_argmax<<<(T + 255) / 256, 256, 0, stream>>>(tlabel, tlab, T, C);
  k_sq<<<NMAX, 64, 0, stream>>>(source, target, nsd_p, sq, S_total, T, D);
  k_count<<<(NMAX + 255) / 256, 256, 0, stream>>>(slab, tlab, nsd_p, cnt, srccnt, tgtcnt, S_total, T);
  k_scan<<<1, 1, 0, stream>>>(cnt, offset, alloc, tprefix, misc, C);
  k_assign<<<(NMAX + 255) / 256, 256, 0, stream>>>(slab, tlab, nsd_p, sq, alloc, perm, sqc, sgnc, S_total, T);
  k_gather<<<NMAX, 64, 0, stream>>>(source, target, nsd_p, perm, compact, S_total, T, D);
  k_colsum<<<dim3(C, D / 64), 64, 0, stream>>>(compact, cnt, offset, normsum, D);
  k_sqsum<<<C, 64, 0, stream>>>(sqc, cnt, offset, sqsum);
  k_bw<<<1, 64, 0, stream>>>(cnt, sqsum, normsum, bwArr, C);
  k_pairs<<<1024, 256, 0, stream>>>(compact, sqc, sgnc, cnt, offset, tprefix, misc, bwArr, losssum, D, C);
  k_final<<<1, 1, 0, stream>>>(cnt, srccnt, tgtcnt, losssum, out, C);
}